// Round 8
// baseline (1910.705 us; speedup 1.0000x reference)
//
#include <hip/hip_runtime.h>

// Problem constants (from reference)
#define NPTS   8192   // N
#define NPT    2048   // NPOINT
#define NS     32     // NSAMPLE
#define CIN    64
#define BATCH  4
// threshold: f32 nearest to 0.64 (numpy/jax weak-type the python float 0.8**2 to f32)
#define R2     0.64f

#define NWORK  252    // worker blocks (grid 256 = 4 fps + 252 workers = #CUs)
#define NQUAD  2048   // 8192 centers / 4 per quad

typedef float __attribute__((ext_vector_type(2))) f32x2;

// ---------------- prep: transpose weights into ws ----------------
__global__ __launch_bounds__(256) void prep_kernel(const float* __restrict__ w1,
                                                   const float* __restrict__ w2,
                                                   float* __restrict__ w1t,
                                                   float* __restrict__ w2t) {
  int i = blockIdx.x * 256 + threadIdx.x;
  if (i < 128 * 67) {
    int o = i / 67, c = i % 67;
    w1t[c * 128 + o] = w1[i];
  }
  if (i < 256 * 128) {
    int o = i >> 7, c = i & 127;
    w2t[c * 256 + o] = w2[i];
  }
}

// ---------------- prep_t: transpose feat (B,C,N) -> FT (B,N,C) ----------------
__global__ __launch_bounds__(256) void prep_t_kernel(const float* __restrict__ feat,
                                                     float* __restrict__ FT) {
  const int b = blockIdx.x >> 7;
  const int n0 = (blockIdx.x & 127) << 6;
  const int tid = threadIdx.x;
  __shared__ float T[64][65];

  const float* F = feat + (size_t)b * CIN * NPTS;
#pragma unroll
  for (int p = 0; p < 16; ++p) {
    int c = p * 4 + (tid >> 6), ln = tid & 63;
    T[c][ln] = F[(size_t)c * NPTS + n0 + ln];
  }
  __syncthreads();
  float* O = FT + (size_t)b * NPTS * CIN;
#pragma unroll
  for (int p = 0; p < 4; ++p) {
    int j = tid >> 2, q = (tid & 3) + p * 4;
    float4 v = make_float4(T[q * 4 + 0][j], T[q * 4 + 1][j],
                           T[q * 4 + 2][j], T[q * 4 + 3][j]);
    *(float4*)&O[(size_t)(n0 + j) * CIN + q * 4] = v;
  }
}

// ---------------- Morton sort (u32 keys, in-LDS bitonic) ----------------
__device__ inline uint32_t part1by2(uint32_t x) {
  x &= 1023u;
  x = (x | (x << 16)) & 0x030000FFu;
  x = (x | (x << 8))  & 0x0300F00Fu;
  x = (x | (x << 4))  & 0x030C30C3u;
  x = (x | (x << 2))  & 0x09249249u;
  return x;
}

__device__ inline uint32_t morton3(float x, float y, float z) {
  int qx = (int)((x + 16.f) * 32.f);
  int qy = (int)((y + 16.f) * 32.f);
  int qz = (int)((z + 16.f) * 32.f);
  qx = qx < 0 ? 0 : (qx > 1023 ? 1023 : qx);
  qy = qy < 0 ? 0 : (qy > 1023 ? 1023 : qy);
  qz = qz < 0 ? 0 : (qz > 1023 ? 1023 : qz);
  return part1by2((uint32_t)qx) | (part1by2((uint32_t)qy) << 1) | (part1by2((uint32_t)qz) << 2);
}

__global__ __launch_bounds__(1024) void sort_kernel(const float* __restrict__ xyz,
                                                    float4* __restrict__ sorted) {
  const int b = blockIdx.x;
  const int tid = threadIdx.x;
  const float* X = xyz + (size_t)b * NPTS * 3;
  __shared__ uint32_t S[NPTS];  // 32 KB

  for (int k = 0; k < 8; ++k) {
    int p = tid + (k << 10);
    uint32_t m = morton3(X[p * 3 + 0], X[p * 3 + 1], X[p * 3 + 2]);
    S[p] = ((m >> 11) << 13) | (uint32_t)p;
  }
  __syncthreads();
  for (unsigned k = 2; k <= NPTS; k <<= 1) {
    for (unsigned j = k >> 1; j > 0; j >>= 1) {
      for (int i = tid; i < NPTS; i += 1024) {
        int l = i ^ (int)j;
        if (l > i) {
          uint32_t a = S[i], c = S[l];
          bool sw = ((i & k) == 0) ? (a > c) : (a < c);
          if (sw) { S[i] = c; S[l] = a; }
        }
      }
      __syncthreads();
    }
  }
  for (int k = 0; k < 8; ++k) {
    int pos = tid + (k << 10);
    int o = (int)(S[pos] & 8191u);
    float4 v;
    v.x = X[o * 3 + 0]; v.y = X[o * 3 + 1]; v.z = X[o * 3 + 2];
    v.w = __int_as_float(o);
    sorted[(size_t)b * NPTS + pos] = v;
  }
}

// ---------------- fused FPS + (ballquery + group + MLP + pool) workers --------
// R7 = R0 (best measured: fused 1559us) with two surgical bit-exact edits.
// R6 proved the 16-wave FPS loop is LATENCY-bound (halving issue with 8
// waves made it slower), so only zero-cost instruction/latency removal can
// help:
//  (a) active-region distance math as float2 ext-vector C code (NO asm, the
//      R1 mistake): clang lowers f32x2 +/- /* to v_pk_add_f32/v_pk_mul_f32
//      on gfx950 with full scheduling freedom. #pragma clang fp contract(off)
//      + explicit temporaries pin the exact ((x2+y2)+z2) rn order ->
//      bit-identical. 96 -> ~64 instr in the active region; degenerates to
//      exactly R0 if the compiler scalarizes.
//  (b) XL stored as padded float4: the tail's dependent center fetch is one
//      ds_read_b128, no x3 address math. Same bits.
// Everything else byte-identical to R0 (workers, ballquery, MLP, stores).

#define DPP_ROR_U32_MAX(v)                                                       \
  {                                                                              \
    uint32_t _t;                                                                 \
    _t = (uint32_t)__builtin_amdgcn_update_dpp(0, (int)(v), 0x121, 0xF, 0xF, false); if (_t > (v)) (v) = _t; \
    _t = (uint32_t)__builtin_amdgcn_update_dpp(0, (int)(v), 0x122, 0xF, 0xF, false); if (_t > (v)) (v) = _t; \
    _t = (uint32_t)__builtin_amdgcn_update_dpp(0, (int)(v), 0x124, 0xF, 0xF, false); if (_t > (v)) (v) = _t; \
    _t = (uint32_t)__builtin_amdgcn_update_dpp(0, (int)(v), 0x128, 0xF, 0xF, false); if (_t > (v)) (v) = _t; \
  }

#define DPP_ROR_U32_MIN(v)                                                       \
  {                                                                              \
    uint32_t _t;                                                                 \
    _t = (uint32_t)__builtin_amdgcn_update_dpp(-1, (int)(v), 0x121, 0xF, 0xF, false); if (_t < (v)) (v) = _t; \
    _t = (uint32_t)__builtin_amdgcn_update_dpp(-1, (int)(v), 0x122, 0xF, 0xF, false); if (_t < (v)) (v) = _t; \
    _t = (uint32_t)__builtin_amdgcn_update_dpp(-1, (int)(v), 0x124, 0xF, 0xF, false); if (_t < (v)) (v) = _t; \
    _t = (uint32_t)__builtin_amdgcn_update_dpp(-1, (int)(v), 0x128, 0xF, 0xF, false); if (_t < (v)) (v) = _t; \
  }

#define CSWAP(i, j)                                                              \
  if (oid[i] > oid[j]) {                                                         \
    int _ti = oid[i]; oid[i] = oid[j]; oid[j] = _ti;                             \
    float _tf;                                                                   \
    _tf = px[i]; px[i] = px[j]; px[j] = _tf;                                     \
    _tf = py[i]; py[i] = py[j]; py[j] = _tf;                                     \
    _tf = pz[i]; pz[i] = pz[j]; pz[j] = _tf;                                     \
  }

__global__ __launch_bounds__(1024, 1) void fused_kernel(
    const float* __restrict__ xyz, const float4* __restrict__ sorted,
    const float* __restrict__ FT,
    const float* __restrict__ w1t, const float* __restrict__ b1,
    const float* __restrict__ w2t, const float* __restrict__ b2,
    float* __restrict__ new_xyz, float* __restrict__ pooled,
    int* __restrict__ progress) {
  const int tid = threadIdx.x;
  const int lane = tid & 63;
  const int wv = tid >> 6;

  // FPS: XL4 0..131072 | rec 131072..131328   Worker: uses first ~100.4 KB
  __shared__ __align__(16) char SM[131328];

  if (blockIdx.x < 4) {
    // ================= FPS role (R0 body + pk-pair update + XL4) ============
    const int b = blockIdx.x;
    float4* XL4 = (float4*)SM;                       // 128 KB padded coords
    uint2 (*rec)[16] = (uint2(*)[16])(SM + 131072);  // [2][16]
    const float* X = xyz + (size_t)b * NPTS * 3;
    const float4* SP = sorted + (size_t)b * NPTS;

    for (int i = tid; i < NPTS; i += 1024) {
      float4 v;
      v.x = X[3 * i + 0]; v.y = X[3 * i + 1]; v.z = X[3 * i + 2]; v.w = 0.f;
      XL4[i] = v;
    }

    float px[8], py[8], pz[8];
    int oid[8];
#pragma unroll
    for (int k = 0; k < 8; ++k) {
      float4 p = SP[tid * 8 + k];
      px[k] = p.x; py[k] = p.y; pz[k] = p.z;
      oid[k] = __float_as_int(p.w);
    }
    CSWAP(0, 1) CSWAP(2, 3) CSWAP(4, 5) CSWAP(6, 7)
    CSWAP(0, 2) CSWAP(1, 3) CSWAP(4, 6) CSWAP(5, 7)
    CSWAP(1, 2) CSWAP(5, 6)
    CSWAP(0, 4) CSWAP(1, 5) CSWAP(2, 6) CSWAP(3, 7)
    CSWAP(2, 4) CSWAP(3, 5)
    CSWAP(1, 2) CSWAP(3, 4) CSWAP(5, 6)

    float bxmin = px[0], bxmax = px[0], bymin = py[0], bymax = py[0], bzmin = pz[0], bzmax = pz[0];
#pragma unroll
    for (int k = 1; k < 8; ++k) {
      bxmin = fminf(bxmin, px[k]); bxmax = fmaxf(bxmax, px[k]);
      bymin = fminf(bymin, py[k]); bymax = fmaxf(bymax, py[k]);
      bzmin = fminf(bzmin, pz[k]); bzmax = fmaxf(bzmax, pz[k]);
    }

    // pack points into pairs; compiler emits v_pk_* for f32x2 arithmetic
    f32x2 px2[4], py2[4], pz2[4], dm2[4];
#pragma unroll
    for (int j = 0; j < 4; ++j) {
      px2[j] = f32x2{px[2 * j], px[2 * j + 1]};
      py2[j] = f32x2{py[2 * j], py[2 * j + 1]};
      pz2[j] = f32x2{pz[2 * j], pz[2 * j + 1]};
      dm2[j] = f32x2{1e10f, 1e10f};
    }

    float cmaxv = 1e10f;
    int   cmaxi = oid[0];
    uint32_t wwm = 0u, wwi = 0u;

    float cx = X[0], cy = X[1], cz = X[2];
    if (tid == 0) {
      new_xyz[(size_t)b * NPT * 3 + 0] = cx;
      new_xyz[(size_t)b * NPT * 3 + 1] = cy;
      new_xyz[(size_t)b * NPT * 3 + 2] = cz;
    }
    __syncthreads();   // XL4 ready

    for (int t = 1; t < NPT; ++t) {
      float ex = fmaxf(fmaxf(bxmin - cx, cx - bxmax), 0.f);
      float ey = fmaxf(fmaxf(bymin - cy, cy - bymax), 0.f);
      float ez = fmaxf(fmaxf(bzmin - cz, cz - bzmax), 0.f);
      float dlb = (ex * ex + ey * ey + ez * ez) * 0.9999f;
      bool act = dlb < cmaxv;

      if (__ballot(act)) {
        if (act) {
#pragma clang fp contract(off)
          const f32x2 cxx = f32x2{cx, cx};
          const f32x2 cyy = f32x2{cy, cy};
          const f32x2 czz = f32x2{cz, cz};
          float mv = -1.0f; int mi = 0;
#pragma unroll
          for (int j = 0; j < 4; ++j) {
            f32x2 dx = px2[j] - cxx;
            f32x2 dy = py2[j] - cyy;
            f32x2 dz = pz2[j] - czz;
            f32x2 xx = dx * dx;
            f32x2 yy = dy * dy;
            f32x2 zz = dz * dz;
            f32x2 s  = xx + yy;
            f32x2 dd = s + zz;
            float m0 = fminf(dm2[j].x, dd.x);
            float m1 = fminf(dm2[j].y, dd.y);
            dm2[j].x = m0; dm2[j].y = m1;
            if (m0 > mv) { mv = m0; mi = oid[2 * j]; }
            if (m1 > mv) { mv = m1; mi = oid[2 * j + 1]; }
          }
          cmaxv = mv; cmaxi = mi;
        }
        uint32_t vb = __float_as_uint(cmaxv);
        uint32_t rm = vb;
        DPP_ROR_U32_MAX(rm)
        uint32_t m0 = (uint32_t)__builtin_amdgcn_readlane((int)rm, 0);
        uint32_t m1 = (uint32_t)__builtin_amdgcn_readlane((int)rm, 16);
        uint32_t m2 = (uint32_t)__builtin_amdgcn_readlane((int)rm, 32);
        uint32_t m3 = (uint32_t)__builtin_amdgcn_readlane((int)rm, 48);
        uint32_t wm = m0 > m1 ? m0 : m1;
        uint32_t wmb = m2 > m3 ? m2 : m3;
        wm = wm > wmb ? wm : wmb;
        unsigned long long em = __ballot(vb == wm);
        uint32_t wi;
        if (__popcll(em) == 1) {
          wi = (uint32_t)__builtin_amdgcn_readlane(cmaxi, __ffsll(em) - 1);
        } else {
          uint32_t ik = (vb == wm) ? (uint32_t)cmaxi : 0xFFFFFFFFu;
          DPP_ROR_U32_MIN(ik)
          uint32_t i0 = (uint32_t)__builtin_amdgcn_readlane((int)ik, 0);
          uint32_t i1 = (uint32_t)__builtin_amdgcn_readlane((int)ik, 16);
          uint32_t i2 = (uint32_t)__builtin_amdgcn_readlane((int)ik, 32);
          uint32_t i3 = (uint32_t)__builtin_amdgcn_readlane((int)ik, 48);
          wi = i0 < i1 ? i0 : i1;
          uint32_t wib = i2 < i3 ? i2 : i3;
          wi = wi < wib ? wi : wib;
        }
        wwm = wm; wwi = wi;
      }

      const int buf = t & 1;
      if (lane == 0) { rec[buf][wv].x = wwm; rec[buf][wv].y = wwi; }
      __syncthreads();

      uint2 r = rec[buf][lane & 15];
      uint32_t bm = r.x;
      DPP_ROR_U32_MAX(bm)
      uint32_t ci = (r.x == bm) ? r.y : 0xFFFFFFFFu;
      DPP_ROR_U32_MIN(ci)
      int sidx = __builtin_amdgcn_readfirstlane((int)ci);

      float4 c4 = XL4[sidx];                  // one ds_read_b128
      cx = c4.x; cy = c4.y; cz = c4.z;

      if (tid == 0) {
        float* o = new_xyz + ((size_t)b * NPT + t) * 3;
        o[0] = cx; o[1] = cy; o[2] = cz;
        if ((t & 15) == 15)   // includes t=2047
          __hip_atomic_store(progress + b, t, __ATOMIC_RELEASE, __HIP_MEMORY_SCOPE_AGENT);
      }
    }
  } else {
    // ================= worker role: bq + group + MLP + pool =================
    float* G    = (float*)SM;                 // 67 x 128
    float* H1   = (float*)(SM + 34304);       // 128 x 128
    int*   lidx = (int*)(SM + 99840);         // 4 x 32
    float* ctr  = (float*)(SM + 100352);      // 4 x 3

    const int wbid = blockIdx.x - 4;          // 0..251

    for (int qg = wbid; qg < NQUAD; qg += NWORK) {
      const int b = qg & 3;                   // quads ordered by squad -> readiness-monotone
      const int s0 = (qg >> 2) * 4;           // first center (in-batch), 4 per quad
      const float* X  = xyz + (size_t)b * NPTS * 3;
      const float* Fp = FT + (size_t)b * NPTS * CIN;

      // 1) wait for fps to produce centers s0..s0+3
      if (tid == 0) {
        while (__hip_atomic_load(progress + b, __ATOMIC_ACQUIRE, __HIP_MEMORY_SCOPE_AGENT) < s0 + 3)
          __builtin_amdgcn_s_sleep(2);
      }
      __syncthreads();

      // 2) centers -> LDS; ball query: one wave per center (waves 0..3)
      if (tid < 12) ctr[tid] = new_xyz[((size_t)b * NPT + s0) * 3 + tid];
      if (wv < 4) {
        const int s = s0 + wv;
        const float cx = new_xyz[((size_t)b * NPT + s) * 3 + 0];
        const float cy = new_xyz[((size_t)b * NPT + s) * 3 + 1];
        const float cz = new_xyz[((size_t)b * NPT + s) * 3 + 2];
        int* out = lidx + wv * NS;
        int found = 0;
        int first = -1;
        for (int base = 0; base < NPTS; base += 64) {
          const int p = base + lane;
          float x = X[p * 3 + 0], y = X[p * 3 + 1], z = X[p * 3 + 2];
          float dx = x - cx, dy = y - cy, dz = z - cz;
          float d2 = __fadd_rn(__fadd_rn(__fmul_rn(dx, dx), __fmul_rn(dy, dy)), __fmul_rn(dz, dz));
          unsigned long long mask = __ballot(d2 < R2);
          if (mask != 0ull && first < 0) first = base + __ffsll((unsigned long long)mask) - 1;
          if (found < NS) {
            if ((mask >> lane) & 1ull) {
              int rank = found + __popcll(mask & ((1ull << lane) - 1ull));
              if (rank < NS) out[rank] = p;
            }
          }
          found += __popcll(mask);
          if (found >= NS) break;
        }
        if (found < NS) {
          int pad = (first < 0) ? 0 : first;
          if (lane >= found && lane < NS) out[lane] = pad;
        }
      }
      __syncthreads();

      // 3) G fill: feature rows via point-major FT (coalesced), rel-xyz rows
      {
        int j = tid >> 3, q = tid & 7;       // 128 points x 8 chunks
        int p = lidx[j];
        const float4* row = (const float4*)(Fp + (size_t)p * CIN);
        float4 v0 = row[q * 2 + 0];
        float4 v1 = row[q * 2 + 1];
        float vs[8] = {v0.x, v0.y, v0.z, v0.w, v1.x, v1.y, v1.z, v1.w};
#pragma unroll
        for (int i = 0; i < 8; ++i)
          G[(3 + q * 8 + i) * 128 + j] = vs[i];
      }
      if (tid < 384) {
        int c = tid >> 7, j = tid & 127;
        int p = lidx[j];
        G[c * 128 + j] = X[p * 3 + c] - ctr[(j >> 5) * 3 + c];
      }
      __syncthreads();

      // 4) H1 = relu(W1 @ G + b1): 128 x 128, each thread 4o x 4j
      {
        const int oi = tid >> 5, ji = tid & 31;
        const int o0 = oi * 4, j0 = ji * 4;
        float acc[4][4];
#pragma unroll
        for (int i = 0; i < 4; ++i)
#pragma unroll
          for (int jj = 0; jj < 4; ++jj) acc[i][jj] = 0.f;
#pragma unroll 4
        for (int c = 0; c < 67; ++c) {
          float4 g  = *(const float4*)&G[c * 128 + j0];
          float4 wf = *(const float4*)&w1t[c * 128 + o0];
          float ga[4] = {g.x, g.y, g.z, g.w};
          float wa[4] = {wf.x, wf.y, wf.z, wf.w};
#pragma unroll
          for (int i = 0; i < 4; ++i)
#pragma unroll
            for (int jj = 0; jj < 4; ++jj)
              acc[i][jj] = fmaf(wa[i], ga[jj], acc[i][jj]);
        }
        float4 bb = *(const float4*)&b1[o0];
        float ba[4] = {bb.x, bb.y, bb.z, bb.w};
#pragma unroll
        for (int i = 0; i < 4; ++i) {
          float4 h;
          h.x = fmaxf(acc[i][0] + ba[i], 0.f);
          h.y = fmaxf(acc[i][1] + ba[i], 0.f);
          h.z = fmaxf(acc[i][2] + ba[i], 0.f);
          h.w = fmaxf(acc[i][3] + ba[i], 0.f);
          *(float4*)&H1[(o0 + i) * 128 + j0] = h;
        }
      }
      __syncthreads();

      // 5) H2 = relu(W2 @ H1 + b2): 256 x 128, thread 8o x 4j, then maxpool
      {
        const int oi = tid >> 5, ji = tid & 31;
        const int o0 = oi * 8, j0 = ji * 4;
        float acc[8][4];
#pragma unroll
        for (int i = 0; i < 8; ++i)
#pragma unroll
          for (int jj = 0; jj < 4; ++jj) acc[i][jj] = 0.f;
#pragma unroll 2
        for (int c = 0; c < 128; ++c) {
          float4 h  = *(const float4*)&H1[c * 128 + j0];
          float4 wa4 = *(const float4*)&w2t[c * 256 + o0];
          float4 wb4 = *(const float4*)&w2t[c * 256 + o0 + 4];
          float ha[4] = {h.x, h.y, h.z, h.w};
          float wa[8] = {wa4.x, wa4.y, wa4.z, wa4.w, wb4.x, wb4.y, wb4.z, wb4.w};
#pragma unroll
          for (int i = 0; i < 8; ++i)
#pragma unroll
            for (int jj = 0; jj < 4; ++jj)
              acc[i][jj] = fmaf(wa[i], ha[jj], acc[i][jj]);
        }
        float4 b2a = *(const float4*)&b2[o0];
        float4 b2b = *(const float4*)&b2[o0 + 4];
        float bb[8] = {b2a.x, b2a.y, b2a.z, b2a.w, b2b.x, b2b.y, b2b.z, b2b.w};
        float m[8];
#pragma unroll
        for (int i = 0; i < 8; ++i) {
          float v0 = fmaxf(acc[i][0] + bb[i], 0.f);
          float v1 = fmaxf(acc[i][1] + bb[i], 0.f);
          float v2 = fmaxf(acc[i][2] + bb[i], 0.f);
          float v3 = fmaxf(acc[i][3] + bb[i], 0.f);
          m[i] = fmaxf(fmaxf(v0, v1), fmaxf(v2, v3));
        }
        // ji&7 groups (8 lanes x 4 j = 32 samples = one center); xor 1,2,4
        // stays within each 8-lane group.
#pragma unroll
        for (int off = 1; off < 8; off <<= 1)
#pragma unroll
          for (int i = 0; i < 8; ++i) m[i] = fmaxf(m[i], __shfl_xor(m[i], off));
        if ((ji & 7) == 0) {
          int sidx = s0 + (ji >> 3);
#pragma unroll
          for (int i = 0; i < 8; ++i)
            pooled[((size_t)b * 256 + o0 + i) * (size_t)NPT + sidx] = m[i];
        }
      }
    }
  }
}

extern "C" void kernel_launch(void* const* d_in, const int* in_sizes, int n_in,
                              void* d_out, int out_size, void* d_ws, size_t ws_size,
                              hipStream_t stream) {
  (void)in_sizes; (void)n_in; (void)out_size; (void)ws_size;
  const float* xyz  = (const float*)d_in[0];   // (4,8192,3)
  const float* feat = (const float*)d_in[1];   // (4,64,8192)
  const float* w1   = (const float*)d_in[2];   // (128,67)
  const float* b1   = (const float*)d_in[3];   // (128)
  const float* w2   = (const float*)d_in[4];   // (256,128)
  const float* b2   = (const float*)d_in[5];   // (256)

  float* out     = (float*)d_out;
  float* new_xyz = out;                        // (4,2048,3)
  float* pooled  = out + (size_t)BATCH * NPT * 3;  // (4,256,2048)

  char* ws = (char*)d_ws;
  float*  w1t      = (float*)ws;                       // 34304 B
  float*  w2t      = (float*)(ws + 34304);             // 131072 B -> 165376
  float4* sorted   = (float4*)(ws + 165376);           // 524288 B -> 689664
  float*  FT       = (float*)(ws + 689664);            // 8388608 B -> 9078272
  int*    progress = (int*)(ws + 9078272);             // 16 B

  prep_kernel<<<128, 256, 0, stream>>>(w1, w2, w1t, w2t);
  prep_t_kernel<<<BATCH * 128, 256, 0, stream>>>(feat, FT);
  sort_kernel<<<BATCH, 1024, 0, stream>>>(xyz, sorted);
  (void)hipMemsetAsync(progress, 0, 16, stream);
  fused_kernel<<<256, 1024, 0, stream>>>(xyz, sorted, FT, w1t, b1, w2t, b2,
                                         new_xyz, pooled, progress);
}